// Round 7
// baseline (1076.634 us; speedup 1.0000x reference)
//
#include <hip/hip_runtime.h>
#include <hip/hip_bf16.h>

#define N_TOK 32768
#define DIM 1024
#define OUTD 1024
#define NEXP 64

typedef __attribute__((ext_vector_type(4))) float f32x4;
typedef __attribute__((ext_vector_type(8))) short bf16x8;

__device__ __forceinline__ unsigned short f2bf(float f) {
    unsigned int u = __builtin_bit_cast(unsigned int, f);
    u += 0x7FFFu + ((u >> 16) & 1u);   // RNE
    return (unsigned short)(u >> 16);
}

#define GLOAD16(gp, lp) \
    __builtin_amdgcn_global_load_lds((const __attribute__((address_space(1))) void*)(gp), \
                                     (__attribute__((address_space(3))) void*)(lp), 16, 0, 0)

// ---------------- prep: gate (blocks 0..511, LDS-hist) + W transpose (512..16895) ----------------
// (unchanged from R5/R6 — verified conflict-free)
__global__ __launch_bounds__(256) void prep_kernel(const float* __restrict__ x,
        const float* __restrict__ gw, const float* __restrict__ gb,
        const float* __restrict__ ew,
        int* __restrict__ sel, int* __restrict__ nflag, int* __restrict__ flags,
        int* __restrict__ counts,
        unsigned short* __restrict__ xb, unsigned short* __restrict__ wt)
{
    __shared__ __align__(16) char smem[18688];
    int tid = threadIdx.x;

    if (blockIdx.x < 512) {
        float (*xs)[36]  = (float(*)[36])smem;
        float (*wsm)[36] = (float(*)[36])(smem + 9216);
        int* h = (int*)(smem + 18432);
        if (tid < NEXP) h[tid] = 0;
        int t0 = blockIdx.x * 64;
        int tg = tid >> 4, eg = tid & 15;

        float acc[4][4];
#pragma unroll
        for (int i = 0; i < 4; i++)
#pragma unroll
            for (int j = 0; j < 4; j++) acc[i][j] = 0.f;

        for (int k0 = 0; k0 < DIM; k0 += 32) {
            __syncthreads();
#pragma unroll
            for (int q = 0; q < 2; q++) {
                int cidx = tid + q * 256;
                int r = cidx >> 3, c4 = (cidx & 7) * 4;
                *reinterpret_cast<float4*>(&xs[r][c4]) =
                    *reinterpret_cast<const float4*>(&x[(size_t)(t0 + r) * DIM + k0 + c4]);
                *reinterpret_cast<float4*>(&wsm[r][c4]) =
                    *reinterpret_cast<const float4*>(&gw[(size_t)r * DIM + k0 + c4]);
            }
            __syncthreads();
            if (xb) {
                int r = tid >> 2, cc = (tid & 3) * 8;
                float4 v0 = *reinterpret_cast<const float4*>(&xs[r][cc]);
                float4 v1 = *reinterpret_cast<const float4*>(&xs[r][cc + 4]);
                uint4 p;
                p.x = (unsigned int)f2bf(v0.x) | ((unsigned int)f2bf(v0.y) << 16);
                p.y = (unsigned int)f2bf(v0.z) | ((unsigned int)f2bf(v0.w) << 16);
                p.z = (unsigned int)f2bf(v1.x) | ((unsigned int)f2bf(v1.y) << 16);
                p.w = (unsigned int)f2bf(v1.z) | ((unsigned int)f2bf(v1.w) << 16);
                *reinterpret_cast<uint4*>(&xb[(size_t)(t0 + r) * DIM + k0 + cc]) = p;
            }
#pragma unroll
            for (int kk4 = 0; kk4 < 8; kk4++) {
                float4 xv[4], wv[4];
#pragma unroll
                for (int i = 0; i < 4; i++)
                    xv[i] = *reinterpret_cast<const float4*>(&xs[tg + 16 * i][kk4 * 4]);
#pragma unroll
                for (int j = 0; j < 4; j++)
                    wv[j] = *reinterpret_cast<const float4*>(&wsm[eg + 16 * j][kk4 * 4]);
#pragma unroll
                for (int i = 0; i < 4; i++)
#pragma unroll
                    for (int j = 0; j < 4; j++) {
                        acc[i][j] = fmaf(xv[i].x, wv[j].x, acc[i][j]);
                        acc[i][j] = fmaf(xv[i].y, wv[j].y, acc[i][j]);
                        acc[i][j] = fmaf(xv[i].z, wv[j].z, acc[i][j]);
                        acc[i][j] = fmaf(xv[i].w, wv[j].w, acc[i][j]);
                    }
            }
        }
#pragma unroll
        for (int j = 0; j < 4; j++) {
            float b = gb[eg + 16 * j];
#pragma unroll
            for (int i = 0; i < 4; i++) acc[i][j] += b;
        }
#pragma unroll
        for (int i = 0; i < 4; i++) {
            float m1 = -1e30f, m2 = -1e30f; int e1 = 0;
#pragma unroll
            for (int j = 0; j < 4; j++) {
                float v = acc[i][j]; int e = eg + 16 * j;
                if (v > m1) { m2 = m1; m1 = v; e1 = e; }
                else if (v > m2) m2 = v;
            }
#pragma unroll
            for (int d = 1; d < 16; d <<= 1) {
                float om1 = __shfl_xor(m1, d, 16);
                float om2 = __shfl_xor(m2, d, 16);
                int   oe1 = __shfl_xor(e1, d, 16);
                if (om1 > m1 || (om1 == m1 && oe1 < e1)) {
                    m2 = fmaxf(om2, m1); m1 = om1; e1 = oe1;
                } else {
                    m2 = fmaxf(m2, om1);
                }
            }
            if (eg == 0) {
                int t = t0 + tg + 16 * i;
                sel[t] = e1;
                atomicAdd(&h[e1], 1);
                if (m1 - m2 < 1e-3f) {
                    int idx = atomicAdd(nflag, 1);
                    if (idx < 4096) flags[idx] = t;
                }
            }
        }
        __syncthreads();
        if (tid < NEXP && h[tid]) atomicAdd(&counts[tid], h[tid]);
    } else {
        if (!wt) return;
        unsigned short* ts = (unsigned short*)smem;   // [64 o][72]
        int lin = blockIdx.x - 512;
        int e = lin >> 8;
        int d0 = (lin & 15) * 64, o0 = ((lin >> 4) & 15) * 64;
        const float* src = ew + (size_t)e * (DIM * OUTD);
        int og = tid & 7;
        int dl = tid >> 3;
#pragma unroll
        for (int i = 0; i < 2; i++) {
            int d = dl + 32 * i;
            const float* sr = &src[(size_t)(d0 + d) * OUTD + o0 + og * 8];
            float4 v0 = *reinterpret_cast<const float4*>(sr);
            float4 v1 = *reinterpret_cast<const float4*>(sr + 4);
            unsigned short b[8] = { f2bf(v0.x), f2bf(v0.y), f2bf(v0.z), f2bf(v0.w),
                                    f2bf(v1.x), f2bf(v1.y), f2bf(v1.z), f2bf(v1.w) };
            int dg = d >> 3, dr = d & 7;
#pragma unroll
            for (int k = 0; k < 8; k++) {
                int o = og * 8 + k;
                int key = (o & 7) ^ ((o >> 3) & 7);
                ts[o * 72 + ((dg ^ key) << 3) + dr] = b[k];
            }
        }
        __syncthreads();
        unsigned short* dst = wt + (size_t)e * (DIM * OUTD);
        int dc = tid & 7;
        int ol = tid >> 3;
#pragma unroll
        for (int i = 0; i < 2; i++) {
            int o = ol + 32 * i;
            int key = (o & 7) ^ ((o >> 3) & 7);
            uint4 v = *reinterpret_cast<const uint4*>(&ts[o * 72 + ((dc ^ key) << 3)]);
            *reinterpret_cast<uint4*>(&dst[(size_t)(o0 + o) * DIM + d0 + dc * 8]) = v;
        }
    }
}

__global__ __launch_bounds__(64) void gate_fix_kernel(const float* __restrict__ x,
        const float* __restrict__ gw, const float* __restrict__ gb,
        int* __restrict__ sel, const int* __restrict__ nflag, const int* __restrict__ flags,
        int* __restrict__ counts)
{
    int n = *nflag; if (n > 4096) n = 4096;
    int b = blockIdx.x;
    if (b >= n) return;
    int t = flags[b];
    int e = threadIdx.x;
    const float* xr = x + (size_t)t * DIM;
    const float* wr = gw + (size_t)e * DIM;
    double acc = (double)gb[e];
    for (int k = 0; k < DIM; k += 4) {
        acc += (double)xr[k]   * (double)wr[k];
        acc += (double)xr[k+1] * (double)wr[k+1];
        acc += (double)xr[k+2] * (double)wr[k+2];
        acc += (double)xr[k+3] * (double)wr[k+3];
    }
    double m1 = acc; int e1 = e;
#pragma unroll
    for (int d = 1; d < 64; d <<= 1) {
        double om1 = __shfl_xor(m1, d, 64);
        int   oe1  = __shfl_xor(e1, d, 64);
        if (om1 > m1 || (om1 == m1 && oe1 < e1)) { m1 = om1; e1 = oe1; }
    }
    if (e == 0) {
        int eOld = sel[t];
        if (eOld != e1) {
            sel[t] = e1;
            atomicSub(&counts[eOld], 1);
            atomicAdd(&counts[e1], 1);
        }
    }
}

__global__ void sched_kernel(const int* __restrict__ counts, int* __restrict__ offsets,
                             int* __restrict__ schedE, int* __restrict__ schedR,
                             int* __restrict__ totalRB, int rowsShift)
{
    int e = threadIdx.x;
    int c = counts[e];
    int v = c;
#pragma unroll
    for (int d = 1; d < 64; d <<= 1) { int y = __shfl_up(v, d, 64); if (e >= d) v += y; }
    offsets[e] = v - c;
    if (e == 63) offsets[NEXP] = v;
    int rows = 1 << rowsShift;
    int nb = (c + rows - 1) >> rowsShift;
    int rbv = nb;
#pragma unroll
    for (int d = 1; d < 64; d <<= 1) { int y = __shfl_up(rbv, d, 64); if (e >= d) rbv += y; }
    int rbBase = rbv - nb;
    for (int i = 0; i < nb; i++) { schedE[rbBase + i] = e; schedR[rbBase + i] = i << rowsShift; }
    if (e == 63) *totalRB = rbv;
}

__global__ __launch_bounds__(256) void scatter_kernel(const int* __restrict__ sel,
        const int* __restrict__ offsets, int* __restrict__ cursor, int* __restrict__ perm)
{
    int t = blockIdx.x * 256 + threadIdx.x;
    int e = sel[t];
    int pos = offsets[e] + atomicAdd(&cursor[e], 1);
    perm[pos] = t;
}

// ---------------- grouped expert GEMM, 256x256x32 bf16 MFMA, 2-buf, 2 blocks/CU ----------------
// LDS exactly 64 KB (2 x [2 bufs x 256 x 32] bf16, no toks[]) -> two blocks co-reside
// per CU; cross-block wave overlap hides load latency (m114 mechanism).
// decode keeps R6's XCD A-sharing: xcd=idx&7, cb=(idx>>3)&3, rb=(idx>>5)*8+xcd.
// Counted vmcnt(4): next tile's 4 loads stay in flight across compute.
__global__ __launch_bounds__(512, 4) void moe_gemm5(
        const unsigned short* __restrict__ xb, const unsigned short* __restrict__ wt,
        const float* __restrict__ eb,
        const int* __restrict__ perm, const int* __restrict__ offsets,
        const int* __restrict__ counts, const int* __restrict__ schedE,
        const int* __restrict__ schedR, const int* __restrict__ totalRB,
        float* __restrict__ out)
{
    int idx = blockIdx.x;
    int xcd = idx & 7;
    int s = idx >> 3;
    int cb = s & 3;
    int rb = (s >> 2) * 8 + xcd;
    if (rb >= *totalRB) return;
    int e = schedE[rb], r0 = schedR[rb];
    int cnt = counts[e], base = offsets[e];

    __shared__ __align__(16) unsigned short As[16384];   // 2 bufs x 256 rows x 32 k
    __shared__ __align__(16) unsigned short Bs[16384];   // total LDS = 65536 B exactly

    int tid = threadIdx.x;
    int lane = tid & 63;
    int wv = tid >> 6;          // 0..7
    int wr = wv >> 2, wc = wv & 3;
    int lr = lane & 15, lg = lane >> 4;

    int rowS = tid >> 2;        // 0..127
    int koff = ((tid & 3) ^ ((tid >> 3) & 3)) * 8;
    int rA1 = r0 + rowS, rA2 = r0 + 128 + rowS;
    int tokA1 = (rA1 < cnt) ? perm[base + rA1] : 0;
    int tokA2 = (rA2 < cnt) ? perm[base + rA2] : 0;

    const unsigned short* wte = wt + ((size_t)e << 20);
    const unsigned short* aSrc1 = xb + (size_t)tokA1 * DIM + koff;
    const unsigned short* aSrc2 = xb + (size_t)tokA2 * DIM + koff;
    const unsigned short* bSrc1 = wte + (size_t)(cb * 256 + rowS) * DIM + koff;
    const unsigned short* bSrc2 = wte + (size_t)(cb * 256 + 128 + rowS) * DIM + koff;

    unsigned short* AsQ0 = As + wv * 512;      // wave-uniform bases (+lane*16B by HW)
    unsigned short* AsQ1 = As + 4096 + wv * 512;
    unsigned short* BsQ0 = Bs + wv * 512;
    unsigned short* BsQ1 = Bs + 4096 + wv * 512;

    f32x4 acc[8][4];
#pragma unroll
    for (int m = 0; m < 8; m++)
#pragma unroll
        for (int n = 0; n < 4; n++)
#pragma unroll
            for (int c = 0; c < 4; c++) acc[m][n][c] = 0.f;

    const char* Asc = (const char*)As;
    const char* Bsc = (const char*)Bs;
    int fko = (lg ^ ((lr >> 1) & 3)) * 16;

    auto stage = [&](int buf, int k0) {
        int off = buf * 8192;   // shorts
        GLOAD16(bSrc1 + k0, BsQ0 + off);
        GLOAD16(bSrc2 + k0, BsQ1 + off);
        GLOAD16(aSrc1 + k0, AsQ0 + off);
        GLOAD16(aSrc2 + k0, AsQ1 + off);
    };
    auto compute = [&](int buf) {
        int boff = buf * 16384; // bytes
        bf16x8 bfr[4];
#pragma unroll
        for (int n = 0; n < 4; n++) {
            int row = wc * 64 + n * 16 + lr;
            bfr[n] = *reinterpret_cast<const bf16x8*>(Bsc + boff + (row << 6) + fko);
        }
        __builtin_amdgcn_s_setprio(1);
#pragma unroll
        for (int m = 0; m < 8; m++) {
            int row = wr * 128 + m * 16 + lr;
            bf16x8 afr = *reinterpret_cast<const bf16x8*>(Asc + boff + (row << 6) + fko);
#pragma unroll
            for (int n = 0; n < 4; n++)
                acc[m][n] = __builtin_amdgcn_mfma_f32_16x16x32_bf16(afr, bfr[n], acc[m][n], 0, 0, 0);
        }
        __builtin_amdgcn_s_setprio(0);
    };

    // prologue: two tiles in flight (perm loads drained before stage addresses form)
    stage(0, 0);
    stage(1, 32);

#pragma unroll 1
    for (int t = 0; t < 30; ++t) {
        asm volatile("s_waitcnt vmcnt(4)" ::: "memory");   // tile t landed (own-wave)
        __builtin_amdgcn_s_barrier();                      // publish to all waves
        compute(t & 1);
        __builtin_amdgcn_s_barrier();                      // all reads of buf (t&1) done
        stage(t & 1, (t + 2) * 32);                        // refill with tile t+2
    }
    // tails: tile 30 (buf 0), tile 31 (buf 1)
    asm volatile("s_waitcnt vmcnt(4)" ::: "memory");
    __builtin_amdgcn_s_barrier();
    compute(0);
    asm volatile("s_waitcnt vmcnt(0)" ::: "memory");
    __builtin_amdgcn_s_barrier();
    compute(1);

    // epilogue: C/D layout col = lane&15, row = (lane>>4)*4 + i
    float bias[4];
#pragma unroll
    for (int n = 0; n < 4; n++)
        bias[n] = eb[e * OUTD + cb * 256 + wc * 64 + n * 16 + lr];
#pragma unroll
    for (int m = 0; m < 8; m++) {
        int rowLoc = wr * 128 + m * 16 + lg * 4;
#pragma unroll
        for (int i2 = 0; i2 < 4; i2++) {
            int r = r0 + rowLoc + i2;
            if (r < cnt) {
                int tk = perm[base + r];
#pragma unroll
                for (int n = 0; n < 4; n++) {
                    int oc = cb * 256 + wc * 64 + n * 16 + lr;
                    out[(size_t)tk * OUTD + oc] = acc[m][n][i2] + bias[n];
                }
            }
        }
    }
}

// ---------------- legacy (R1) GEMM — fallback if ws too small ----------------
__global__ __launch_bounds__(256) void moe_gemm_legacy(const float* __restrict__ x,
        const float* __restrict__ ew, const float* __restrict__ eb,
        const int* __restrict__ perm, const int* __restrict__ offsets,
        const int* __restrict__ counts, const int* __restrict__ schedE,
        const int* __restrict__ schedR, const int* __restrict__ totalRB,
        float* __restrict__ out)
{
    int rb = blockIdx.x;
    if (rb >= *totalRB) return;
    int cb = blockIdx.y;
    int e = schedE[rb], r0 = schedR[rb];
    int cnt = counts[e], base = offsets[e];

    __shared__ __align__(16) unsigned short As[128][40];
    __shared__ __align__(16) unsigned short Bs[128][40];
    __shared__ int toks[128];

    int tid = threadIdx.x;
    if (tid < 128) {
        int r = r0 + tid;
        toks[tid] = (r < cnt) ? perm[base + r] : -1;
    }
    __syncthreads();

    int lane = tid & 63;
    int wave = tid >> 6;
    int wr = wave >> 1, wc = wave & 1;
    int lr = lane & 15, lg = lane >> 4;

    f32x4 acc[4][4];
#pragma unroll
    for (int m = 0; m < 4; m++)
#pragma unroll
        for (int n = 0; n < 4; n++)
#pragma unroll
            for (int c = 0; c < 4; c++) acc[m][n][c] = 0.f;

    int aRow[4]; int aTok[4];
#pragma unroll
    for (int q = 0; q < 4; q++) {
        aRow[q] = (tid >> 3) + q * 32;
        int tk = toks[aRow[q]];
        aTok[q] = (tk < 0) ? 0 : tk;
    }
    int ac4 = tid & 7;
    int d0 = (tid >> 5) * 4;
    int o_lane = tid & 31;
    const float* wb = ew + (size_t)e * (DIM * OUTD) + (size_t)cb * 128;

    for (int k0 = 0; k0 < DIM; k0 += 32) {
        float4 av[4];
#pragma unroll
        for (int q = 0; q < 4; q++)
            av[q] = *reinterpret_cast<const float4*>(&x[(size_t)aTok[q] * DIM + k0 + ac4 * 4]);
        float bv[4][4];
#pragma unroll
        for (int i2 = 0; i2 < 4; i2++)
#pragma unroll
            for (int j = 0; j < 4; j++)
                bv[i2][j] = wb[(size_t)(k0 + d0 + i2) * OUTD + o_lane + 32 * j];

        __syncthreads();
#pragma unroll
        for (int q = 0; q < 4; q++) {
            uint2 p;
            p.x = (unsigned int)f2bf(av[q].x) | ((unsigned int)f2bf(av[q].y) << 16);
            p.y = (unsigned int)f2bf(av[q].z) | ((unsigned int)f2bf(av[q].w) << 16);
            *reinterpret_cast<uint2*>(&As[aRow[q]][ac4 * 4]) = p;
        }
#pragma unroll
        for (int j = 0; j < 4; j++) {
            uint2 p;
            p.x = (unsigned int)f2bf(bv[0][j]) | ((unsigned int)f2bf(bv[1][j]) << 16);
            p.y = (unsigned int)f2bf(bv[2][j]) | ((unsigned int)f2bf(bv[3][j]) << 16);
            *reinterpret_cast<uint2*>(&Bs[o_lane + 32 * j][d0]) = p;
        }
        __syncthreads();

        bf16x8 bfr[4];
#pragma unroll
        for (int n = 0; n < 4; n++)
            bfr[n] = *reinterpret_cast<const bf16x8*>(&Bs[wc * 64 + n * 16 + lr][lg * 8]);
#pragma unroll
        for (int m = 0; m < 4; m++) {
            bf16x8 afr = *reinterpret_cast<const bf16x8*>(&As[wr * 64 + m * 16 + lr][lg * 8]);
#pragma unroll
            for (int n = 0; n < 4; n++)
                acc[m][n] = __builtin_amdgcn_mfma_f32_16x16x32_bf16(afr, bfr[n], acc[m][n], 0, 0, 0);
        }
    }

#pragma unroll
    for (int n = 0; n < 4; n++) {
        int oc = cb * 128 + wc * 64 + n * 16 + lr;
        float bias = eb[e * OUTD + oc];
#pragma unroll
        for (int m = 0; m < 4; m++) {
#pragma unroll
            for (int i2 = 0; i2 < 4; i2++) {
                int rr = wr * 64 + m * 16 + lg * 4 + i2;
                int tk = toks[rr];
                if (tk >= 0)
                    out[(size_t)tk * OUTD + oc] = acc[m][n][i2] + bias;
            }
        }
    }
}

extern "C" void kernel_launch(void* const* d_in, const int* in_sizes, int n_in,
                              void* d_out, int out_size, void* d_ws, size_t ws_size,
                              hipStream_t stream)
{
    const float* x  = (const float*)d_in[0];
    const float* gw = (const float*)d_in[1];
    const float* gb = (const float*)d_in[2];
    const float* ew = (const float*)d_in[3];
    const float* eb = (const float*)d_in[4];
    float* out = (float*)d_out;

    char* ws = (char*)d_ws;
    int* counts  = (int*)(ws + 0);
    int* cursor  = (int*)(ws + 256);
    int* offsets = (int*)(ws + 512);
    int* totalRB = (int*)(ws + 1024);
    int* nflag   = (int*)(ws + 1028);
    int* flags   = (int*)(ws + 1032);
    int* schedE  = (int*)(ws + 20480);
    int* schedR  = (int*)(ws + 22528);
    int* sel     = (int*)(ws + 24576);
    int* perm    = (int*)(ws + 155648);

    const size_t WT_OFF   = (size_t)1 << 20;
    const size_t WT_BYTES = (size_t)NEXP * DIM * OUTD * 2;   // 128 MiB
    const size_t XB_OFF   = WT_OFF + WT_BYTES;
    const size_t XB_BYTES = (size_t)N_TOK * DIM * 2;         // 64 MiB
    int mode = (ws_size >= XB_OFF + XB_BYTES) ? 2 : 0;
    unsigned short* wt = (mode == 2) ? (unsigned short*)(ws + WT_OFF) : nullptr;
    unsigned short* xb = (mode == 2) ? (unsigned short*)(ws + XB_OFF) : nullptr;

    hipMemsetAsync(ws, 0, 2048, stream);

    prep_kernel<<<dim3(512 + ((mode == 2) ? 16384 : 0)), 256, 0, stream>>>(
        x, gw, gb, ew, sel, nflag, flags, counts, xb, wt);
    gate_fix_kernel<<<dim3(4096), 64, 0, stream>>>(x, gw, gb, sel, nflag, flags, counts);
    sched_kernel<<<dim3(1), 64, 0, stream>>>(counts, offsets, schedE, schedR, totalRB,
                                             (mode == 2) ? 8 : 7);
    scatter_kernel<<<dim3(N_TOK / 256), 256, 0, stream>>>(sel, offsets, cursor, perm);

    if (mode == 2)
        moe_gemm5<<<dim3(768), 512, 0, stream>>>(xb, wt, eb, perm, offsets, counts,
                                                 schedE, schedR, totalRB, out);
    else
        moe_gemm_legacy<<<dim3(320, 8), 256, 0, stream>>>(x, ew, eb, perm, offsets, counts,
                                                          schedE, schedR, totalRB, out);
}

// Round 8
// 381.745 us; speedup vs baseline: 2.8203x; 2.8203x over previous
//
#include <hip/hip_runtime.h>
#include <hip/hip_bf16.h>

#define N_TOK 32768
#define DIM 1024
#define OUTD 1024
#define NEXP 64

typedef __attribute__((ext_vector_type(4))) float f32x4;
typedef __attribute__((ext_vector_type(8))) short bf16x8;

__device__ __forceinline__ unsigned short f2bf(float f) {
    unsigned int u = __builtin_bit_cast(unsigned int, f);
    u += 0x7FFFu + ((u >> 16) & 1u);   // RNE
    return (unsigned short)(u >> 16);
}

#define GLOAD16(gp, lp) \
    __builtin_amdgcn_global_load_lds((const __attribute__((address_space(1))) void*)(gp), \
                                     (__attribute__((address_space(3))) void*)(lp), 16, 0, 0)

// ---------------- prep: gate (blocks 0..511, LDS-hist) + W transpose (512..16895) ----------------
// (unchanged from R5-R7 — verified conflict-free)
__global__ __launch_bounds__(256) void prep_kernel(const float* __restrict__ x,
        const float* __restrict__ gw, const float* __restrict__ gb,
        const float* __restrict__ ew,
        int* __restrict__ sel, int* __restrict__ nflag, int* __restrict__ flags,
        int* __restrict__ counts,
        unsigned short* __restrict__ xb, unsigned short* __restrict__ wt)
{
    __shared__ __align__(16) char smem[18688];
    int tid = threadIdx.x;

    if (blockIdx.x < 512) {
        float (*xs)[36]  = (float(*)[36])smem;
        float (*wsm)[36] = (float(*)[36])(smem + 9216);
        int* h = (int*)(smem + 18432);
        if (tid < NEXP) h[tid] = 0;
        int t0 = blockIdx.x * 64;
        int tg = tid >> 4, eg = tid & 15;

        float acc[4][4];
#pragma unroll
        for (int i = 0; i < 4; i++)
#pragma unroll
            for (int j = 0; j < 4; j++) acc[i][j] = 0.f;

        for (int k0 = 0; k0 < DIM; k0 += 32) {
            __syncthreads();
#pragma unroll
            for (int q = 0; q < 2; q++) {
                int cidx = tid + q * 256;
                int r = cidx >> 3, c4 = (cidx & 7) * 4;
                *reinterpret_cast<float4*>(&xs[r][c4]) =
                    *reinterpret_cast<const float4*>(&x[(size_t)(t0 + r) * DIM + k0 + c4]);
                *reinterpret_cast<float4*>(&wsm[r][c4]) =
                    *reinterpret_cast<const float4*>(&gw[(size_t)r * DIM + k0 + c4]);
            }
            __syncthreads();
            if (xb) {
                int r = tid >> 2, cc = (tid & 3) * 8;
                float4 v0 = *reinterpret_cast<const float4*>(&xs[r][cc]);
                float4 v1 = *reinterpret_cast<const float4*>(&xs[r][cc + 4]);
                uint4 p;
                p.x = (unsigned int)f2bf(v0.x) | ((unsigned int)f2bf(v0.y) << 16);
                p.y = (unsigned int)f2bf(v0.z) | ((unsigned int)f2bf(v0.w) << 16);
                p.z = (unsigned int)f2bf(v1.x) | ((unsigned int)f2bf(v1.y) << 16);
                p.w = (unsigned int)f2bf(v1.z) | ((unsigned int)f2bf(v1.w) << 16);
                *reinterpret_cast<uint4*>(&xb[(size_t)(t0 + r) * DIM + k0 + cc]) = p;
            }
#pragma unroll
            for (int kk4 = 0; kk4 < 8; kk4++) {
                float4 xv[4], wv[4];
#pragma unroll
                for (int i = 0; i < 4; i++)
                    xv[i] = *reinterpret_cast<const float4*>(&xs[tg + 16 * i][kk4 * 4]);
#pragma unroll
                for (int j = 0; j < 4; j++)
                    wv[j] = *reinterpret_cast<const float4*>(&wsm[eg + 16 * j][kk4 * 4]);
#pragma unroll
                for (int i = 0; i < 4; i++)
#pragma unroll
                    for (int j = 0; j < 4; j++) {
                        acc[i][j] = fmaf(xv[i].x, wv[j].x, acc[i][j]);
                        acc[i][j] = fmaf(xv[i].y, wv[j].y, acc[i][j]);
                        acc[i][j] = fmaf(xv[i].z, wv[j].z, acc[i][j]);
                        acc[i][j] = fmaf(xv[i].w, wv[j].w, acc[i][j]);
                    }
            }
        }
#pragma unroll
        for (int j = 0; j < 4; j++) {
            float b = gb[eg + 16 * j];
#pragma unroll
            for (int i = 0; i < 4; i++) acc[i][j] += b;
        }
#pragma unroll
        for (int i = 0; i < 4; i++) {
            float m1 = -1e30f, m2 = -1e30f; int e1 = 0;
#pragma unroll
            for (int j = 0; j < 4; j++) {
                float v = acc[i][j]; int e = eg + 16 * j;
                if (v > m1) { m2 = m1; m1 = v; e1 = e; }
                else if (v > m2) m2 = v;
            }
#pragma unroll
            for (int d = 1; d < 16; d <<= 1) {
                float om1 = __shfl_xor(m1, d, 16);
                float om2 = __shfl_xor(m2, d, 16);
                int   oe1 = __shfl_xor(e1, d, 16);
                if (om1 > m1 || (om1 == m1 && oe1 < e1)) {
                    m2 = fmaxf(om2, m1); m1 = om1; e1 = oe1;
                } else {
                    m2 = fmaxf(m2, om1);
                }
            }
            if (eg == 0) {
                int t = t0 + tg + 16 * i;
                sel[t] = e1;
                atomicAdd(&h[e1], 1);
                if (m1 - m2 < 1e-3f) {
                    int idx = atomicAdd(nflag, 1);
                    if (idx < 4096) flags[idx] = t;
                }
            }
        }
        __syncthreads();
        if (tid < NEXP && h[tid]) atomicAdd(&counts[tid], h[tid]);
    } else {
        if (!wt) return;
        unsigned short* ts = (unsigned short*)smem;   // [64 o][72]
        int lin = blockIdx.x - 512;
        int e = lin >> 8;
        int d0 = (lin & 15) * 64, o0 = ((lin >> 4) & 15) * 64;
        const float* src = ew + (size_t)e * (DIM * OUTD);
        int og = tid & 7;
        int dl = tid >> 3;
#pragma unroll
        for (int i = 0; i < 2; i++) {
            int d = dl + 32 * i;
            const float* sr = &src[(size_t)(d0 + d) * OUTD + o0 + og * 8];
            float4 v0 = *reinterpret_cast<const float4*>(sr);
            float4 v1 = *reinterpret_cast<const float4*>(sr + 4);
            unsigned short b[8] = { f2bf(v0.x), f2bf(v0.y), f2bf(v0.z), f2bf(v0.w),
                                    f2bf(v1.x), f2bf(v1.y), f2bf(v1.z), f2bf(v1.w) };
            int dg = d >> 3, dr = d & 7;
#pragma unroll
            for (int k = 0; k < 8; k++) {
                int o = og * 8 + k;
                int key = (o & 7) ^ ((o >> 3) & 7);
                ts[o * 72 + ((dg ^ key) << 3) + dr] = b[k];
            }
        }
        __syncthreads();
        unsigned short* dst = wt + (size_t)e * (DIM * OUTD);
        int dc = tid & 7;
        int ol = tid >> 3;
#pragma unroll
        for (int i = 0; i < 2; i++) {
            int o = ol + 32 * i;
            int key = (o & 7) ^ ((o >> 3) & 7);
            uint4 v = *reinterpret_cast<const uint4*>(&ts[o * 72 + ((dc ^ key) << 3)]);
            *reinterpret_cast<uint4*>(&dst[(size_t)(o0 + o) * DIM + d0 + dc * 8]) = v;
        }
    }
}

__global__ __launch_bounds__(64) void gate_fix_kernel(const float* __restrict__ x,
        const float* __restrict__ gw, const float* __restrict__ gb,
        int* __restrict__ sel, const int* __restrict__ nflag, const int* __restrict__ flags,
        int* __restrict__ counts)
{
    int n = *nflag; if (n > 4096) n = 4096;
    int b = blockIdx.x;
    if (b >= n) return;
    int t = flags[b];
    int e = threadIdx.x;
    const float* xr = x + (size_t)t * DIM;
    const float* wr = gw + (size_t)e * DIM;
    double acc = (double)gb[e];
    for (int k = 0; k < DIM; k += 4) {
        acc += (double)xr[k]   * (double)wr[k];
        acc += (double)xr[k+1] * (double)wr[k+1];
        acc += (double)xr[k+2] * (double)wr[k+2];
        acc += (double)xr[k+3] * (double)wr[k+3];
    }
    double m1 = acc; int e1 = e;
#pragma unroll
    for (int d = 1; d < 64; d <<= 1) {
        double om1 = __shfl_xor(m1, d, 64);
        int   oe1  = __shfl_xor(e1, d, 64);
        if (om1 > m1 || (om1 == m1 && oe1 < e1)) { m1 = om1; e1 = oe1; }
    }
    if (e == 0) {
        int eOld = sel[t];
        if (eOld != e1) {
            sel[t] = e1;
            atomicSub(&counts[eOld], 1);
            atomicAdd(&counts[e1], 1);
        }
    }
}

__global__ void sched_kernel(const int* __restrict__ counts, int* __restrict__ offsets,
                             int* __restrict__ schedE, int* __restrict__ schedR,
                             int* __restrict__ totalRB, int rowsShift)
{
    int e = threadIdx.x;
    int c = counts[e];
    int v = c;
#pragma unroll
    for (int d = 1; d < 64; d <<= 1) { int y = __shfl_up(v, d, 64); if (e >= d) v += y; }
    offsets[e] = v - c;
    if (e == 63) offsets[NEXP] = v;
    int rows = 1 << rowsShift;
    int nb = (c + rows - 1) >> rowsShift;
    int rbv = nb;
#pragma unroll
    for (int d = 1; d < 64; d <<= 1) { int y = __shfl_up(rbv, d, 64); if (e >= d) rbv += y; }
    int rbBase = rbv - nb;
    for (int i = 0; i < nb; i++) { schedE[rbBase + i] = e; schedR[rbBase + i] = i << rowsShift; }
    if (e == 63) *totalRB = rbv;
}

__global__ __launch_bounds__(256) void scatter_kernel(const int* __restrict__ sel,
        const int* __restrict__ offsets, int* __restrict__ cursor, int* __restrict__ perm)
{
    int t = blockIdx.x * 256 + threadIdx.x;
    int e = sel[t];
    int pos = offsets[e] + atomicAdd(&cursor[e], 1);
    perm[pos] = t;
}

// ---------------- grouped expert GEMM, 256x128x32 bf16 MFMA, 2-buf, 2 blocks/CU ----------------
// Geometry chosen so occupancy and registers are compatible:
//   8 waves x (64x64 output each) -> acc[4][4] = 64 VGPR/lane  (R7 lesson: 256x256
//   needs 128 acc regs and can NEVER fit 2 blocks/CU; spills catastrophically)
//   LDS = A dbuf 32K + B dbuf 16K = 48 KB -> 2 blocks/CU (96 KB < 160 KB)
// decode: 8 cb-blocks of one rb pinned to one XCD (A-tile L2-shared).
// Counted vmcnt(3): next tile's 3 loads (2A+1B) in flight across compute.
__global__ __launch_bounds__(512, 4) void moe_gemm6(
        const unsigned short* __restrict__ xb, const unsigned short* __restrict__ wt,
        const float* __restrict__ eb,
        const int* __restrict__ perm, const int* __restrict__ offsets,
        const int* __restrict__ counts, const int* __restrict__ schedE,
        const int* __restrict__ schedR, const int* __restrict__ totalRB,
        float* __restrict__ out)
{
    int idx = blockIdx.x;
    int xcd = idx & 7;
    int s = idx >> 3;
    int cb = s & 7;                 // 8 col-blocks of 128
    int rb = (s >> 3) * 8 + xcd;
    if (rb >= *totalRB) return;
    int e = schedE[rb], r0 = schedR[rb];
    int cnt = counts[e], base = offsets[e];

    __shared__ __align__(16) unsigned short As[16384];   // 2 bufs x 256 rows x 32 k (32 KB)
    __shared__ __align__(16) unsigned short Bs[8192];    // 2 bufs x 128 rows x 32 k (16 KB)

    int tid = threadIdx.x;
    int lane = tid & 63;
    int wv = tid >> 6;          // 0..7
    int wr = wv >> 1, wc = wv & 1;      // wave grid: 4 row-groups x 2 col-groups
    int lr = lane & 15, lg = lane >> 4;

    int rowS = tid >> 2;        // 0..127
    int koff = ((tid & 3) ^ ((tid >> 3) & 3)) * 8;   // key = (row>>1)&3 (proven 0-conflict)
    int rA1 = r0 + rowS, rA2 = r0 + 128 + rowS;
    int tokA1 = (rA1 < cnt) ? perm[base + rA1] : 0;
    int tokA2 = (rA2 < cnt) ? perm[base + rA2] : 0;

    const unsigned short* wte = wt + ((size_t)e << 20);
    const unsigned short* aSrc1 = xb + (size_t)tokA1 * DIM + koff;
    const unsigned short* aSrc2 = xb + (size_t)tokA2 * DIM + koff;
    const unsigned short* bSrc1 = wte + (size_t)(cb * 128 + rowS) * DIM + koff;

    unsigned short* AsQ0 = As + wv * 512;          // wave-uniform (+lane*16B by HW)
    unsigned short* AsQ1 = As + 4096 + wv * 512;
    unsigned short* BsQ0 = Bs + wv * 512;

    f32x4 acc[4][4];
#pragma unroll
    for (int m = 0; m < 4; m++)
#pragma unroll
        for (int n = 0; n < 4; n++)
#pragma unroll
            for (int c = 0; c < 4; c++) acc[m][n][c] = 0.f;

    const char* Asc = (const char*)As;
    const char* Bsc = (const char*)Bs;
    int fko = (lg ^ ((lr >> 1) & 3)) * 16;

    auto stage = [&](int buf, int k0) {
        GLOAD16(aSrc1 + k0, AsQ0 + buf * 8192);
        GLOAD16(aSrc2 + k0, AsQ1 + buf * 8192);
        GLOAD16(bSrc1 + k0, BsQ0 + buf * 4096);
    };
    auto compute = [&](int buf) {
        int aoff = buf * 16384;  // bytes
        int boff = buf * 8192;
        bf16x8 bfr[4];
#pragma unroll
        for (int n = 0; n < 4; n++) {
            int row = wc * 64 + n * 16 + lr;
            bfr[n] = *reinterpret_cast<const bf16x8*>(Bsc + boff + (row << 6) + fko);
        }
        __builtin_amdgcn_s_setprio(1);
#pragma unroll
        for (int m = 0; m < 4; m++) {
            int row = wr * 64 + m * 16 + lr;
            bf16x8 afr = *reinterpret_cast<const bf16x8*>(Asc + aoff + (row << 6) + fko);
#pragma unroll
            for (int n = 0; n < 4; n++)
                acc[m][n] = __builtin_amdgcn_mfma_f32_16x16x32_bf16(afr, bfr[n], acc[m][n], 0, 0, 0);
        }
        __builtin_amdgcn_s_setprio(0);
    };

    // prologue: two tiles in flight (6 loads)
    stage(0, 0);
    stage(1, 32);

#pragma unroll 1
    for (int t = 0; t < 30; ++t) {
        asm volatile("s_waitcnt vmcnt(3)" ::: "memory");   // tile t landed (own-wave)
        __builtin_amdgcn_s_barrier();                      // publish to all waves
        compute(t & 1);
        __builtin_amdgcn_s_barrier();                      // all reads of buf (t&1) done
        stage(t & 1, (t + 2) * 32);                        // refill with tile t+2
    }
    asm volatile("s_waitcnt vmcnt(3)" ::: "memory");
    __builtin_amdgcn_s_barrier();
    compute(0);
    asm volatile("s_waitcnt vmcnt(0)" ::: "memory");
    __builtin_amdgcn_s_barrier();
    compute(1);

    // epilogue: C/D layout col = lane&15, row = (lane>>4)*4 + i
    float bias[4];
#pragma unroll
    for (int n = 0; n < 4; n++)
        bias[n] = eb[e * OUTD + cb * 128 + wc * 64 + n * 16 + lr];
#pragma unroll
    for (int m = 0; m < 4; m++) {
        int rowLoc = wr * 64 + m * 16 + lg * 4;
#pragma unroll
        for (int i2 = 0; i2 < 4; i2++) {
            int r = r0 + rowLoc + i2;
            if (r < cnt) {
                int tk = perm[base + r];
#pragma unroll
                for (int n = 0; n < 4; n++) {
                    int oc = cb * 128 + wc * 64 + n * 16 + lr;
                    out[(size_t)tk * OUTD + oc] = acc[m][n][i2] + bias[n];
                }
            }
        }
    }
}

// ---------------- legacy (R1) GEMM — fallback if ws too small ----------------
__global__ __launch_bounds__(256) void moe_gemm_legacy(const float* __restrict__ x,
        const float* __restrict__ ew, const float* __restrict__ eb,
        const int* __restrict__ perm, const int* __restrict__ offsets,
        const int* __restrict__ counts, const int* __restrict__ schedE,
        const int* __restrict__ schedR, const int* __restrict__ totalRB,
        float* __restrict__ out)
{
    int rb = blockIdx.x;
    if (rb >= *totalRB) return;
    int cb = blockIdx.y;
    int e = schedE[rb], r0 = schedR[rb];
    int cnt = counts[e], base = offsets[e];

    __shared__ __align__(16) unsigned short As[128][40];
    __shared__ __align__(16) unsigned short Bs[128][40];
    __shared__ int toks[128];

    int tid = threadIdx.x;
    if (tid < 128) {
        int r = r0 + tid;
        toks[tid] = (r < cnt) ? perm[base + r] : -1;
    }
    __syncthreads();

    int lane = tid & 63;
    int wave = tid >> 6;
    int wr = wave >> 1, wc = wave & 1;
    int lr = lane & 15, lg = lane >> 4;

    f32x4 acc[4][4];
#pragma unroll
    for (int m = 0; m < 4; m++)
#pragma unroll
        for (int n = 0; n < 4; n++)
#pragma unroll
            for (int c = 0; c < 4; c++) acc[m][n][c] = 0.f;

    int aRow[4]; int aTok[4];
#pragma unroll
    for (int q = 0; q < 4; q++) {
        aRow[q] = (tid >> 3) + q * 32;
        int tk = toks[aRow[q]];
        aTok[q] = (tk < 0) ? 0 : tk;
    }
    int ac4 = tid & 7;
    int d0 = (tid >> 5) * 4;
    int o_lane = tid & 31;
    const float* wb = ew + (size_t)e * (DIM * OUTD) + (size_t)cb * 128;

    for (int k0 = 0; k0 < DIM; k0 += 32) {
        float4 av[4];
#pragma unroll
        for (int q = 0; q < 4; q++)
            av[q] = *reinterpret_cast<const float4*>(&x[(size_t)aTok[q] * DIM + k0 + ac4 * 4]);
        float bv[4][4];
#pragma unroll
        for (int i2 = 0; i2 < 4; i2++)
#pragma unroll
            for (int j = 0; j < 4; j++)
                bv[i2][j] = wb[(size_t)(k0 + d0 + i2) * OUTD + o_lane + 32 * j];

        __syncthreads();
#pragma unroll
        for (int q = 0; q < 4; q++) {
            uint2 p;
            p.x = (unsigned int)f2bf(av[q].x) | ((unsigned int)f2bf(av[q].y) << 16);
            p.y = (unsigned int)f2bf(av[q].z) | ((unsigned int)f2bf(av[q].w) << 16);
            *reinterpret_cast<uint2*>(&As[aRow[q]][ac4 * 4]) = p;
        }
#pragma unroll
        for (int j = 0; j < 4; j++) {
            uint2 p;
            p.x = (unsigned int)f2bf(bv[0][j]) | ((unsigned int)f2bf(bv[1][j]) << 16);
            p.y = (unsigned int)f2bf(bv[2][j]) | ((unsigned int)f2bf(bv[3][j]) << 16);
            *reinterpret_cast<uint2*>(&Bs[o_lane + 32 * j][d0]) = p;
        }
        __syncthreads();

        bf16x8 bfr[4];
#pragma unroll
        for (int n = 0; n < 4; n++)
            bfr[n] = *reinterpret_cast<const bf16x8*>(&Bs[wc * 64 + n * 16 + lr][lg * 8]);
#pragma unroll
        for (int m = 0; m < 4; m++) {
            bf16x8 afr = *reinterpret_cast<const bf16x8*>(&As[wr * 64 + m * 16 + lr][lg * 8]);
#pragma unroll
            for (int n = 0; n < 4; n++)
                acc[m][n] = __builtin_amdgcn_mfma_f32_16x16x32_bf16(afr, bfr[n], acc[m][n], 0, 0, 0);
        }
    }

#pragma unroll
    for (int n = 0; n < 4; n++) {
        int oc = cb * 128 + wc * 64 + n * 16 + lr;
        float bias = eb[e * OUTD + oc];
#pragma unroll
        for (int m = 0; m < 4; m++) {
#pragma unroll
            for (int i2 = 0; i2 < 4; i2++) {
                int rr = wr * 64 + m * 16 + lg * 4 + i2;
                int tk = toks[rr];
                if (tk >= 0)
                    out[(size_t)tk * OUTD + oc] = acc[m][n][i2] + bias;
            }
        }
    }
}

extern "C" void kernel_launch(void* const* d_in, const int* in_sizes, int n_in,
                              void* d_out, int out_size, void* d_ws, size_t ws_size,
                              hipStream_t stream)
{
    const float* x  = (const float*)d_in[0];
    const float* gw = (const float*)d_in[1];
    const float* gb = (const float*)d_in[2];
    const float* ew = (const float*)d_in[3];
    const float* eb = (const float*)d_in[4];
    float* out = (float*)d_out;

    char* ws = (char*)d_ws;
    int* counts  = (int*)(ws + 0);
    int* cursor  = (int*)(ws + 256);
    int* offsets = (int*)(ws + 512);
    int* totalRB = (int*)(ws + 1024);
    int* nflag   = (int*)(ws + 1028);
    int* flags   = (int*)(ws + 1032);
    int* schedE  = (int*)(ws + 20480);
    int* schedR  = (int*)(ws + 22528);
    int* sel     = (int*)(ws + 24576);
    int* perm    = (int*)(ws + 155648);

    const size_t WT_OFF   = (size_t)1 << 20;
    const size_t WT_BYTES = (size_t)NEXP * DIM * OUTD * 2;   // 128 MiB
    const size_t XB_OFF   = WT_OFF + WT_BYTES;
    const size_t XB_BYTES = (size_t)N_TOK * DIM * 2;         // 64 MiB
    int mode = (ws_size >= XB_OFF + XB_BYTES) ? 2 : 0;
    unsigned short* wt = (mode == 2) ? (unsigned short*)(ws + WT_OFF) : nullptr;
    unsigned short* xb = (mode == 2) ? (unsigned short*)(ws + XB_OFF) : nullptr;

    hipMemsetAsync(ws, 0, 2048, stream);

    prep_kernel<<<dim3(512 + ((mode == 2) ? 16384 : 0)), 256, 0, stream>>>(
        x, gw, gb, ew, sel, nflag, flags, counts, xb, wt);
    gate_fix_kernel<<<dim3(4096), 64, 0, stream>>>(x, gw, gb, sel, nflag, flags, counts);
    sched_kernel<<<dim3(1), 64, 0, stream>>>(counts, offsets, schedE, schedR, totalRB,
                                             (mode == 2) ? 8 : 7);
    scatter_kernel<<<dim3(N_TOK / 256), 256, 0, stream>>>(sel, offsets, cursor, perm);

    if (mode == 2)
        moe_gemm6<<<dim3(1536), 512, 0, stream>>>(xb, wt, eb, perm, offsets, counts,
                                                  schedE, schedR, totalRB, out);
    else
        moe_gemm_legacy<<<dim3(320, 8), 256, 0, stream>>>(x, ew, eb, perm, offsets, counts,
                                                          schedE, schedR, totalRB, out);
}